// Round 15
// baseline (102.436 us; speedup 1.0000x reference)
//
#include <hip/hip_runtime.h>

// B=32, L=512, D=1024; 7 linear experts + identity, routed per token.
// 3 launches:
//  K1 routeconv_k: block 0 = route via BALLOT count/scatter (no LDS-atomic
//     serialization -- R14's 45us histogram was 512-deep same-address
//     atomics); blocks 1..1792 = W f32->bf16.
//  K2 aconv_k: slot s -> gather+convert A row to Abf[s] (linear) or
//     identity row copy to out.
//  K3 gemm_k: R9's proven schedule: 256 blocks (1/CU), 256x256 tile,
//     8 waves (2Mx4N), BK=64, XOR-swizzled LDS, distinct-array dbuf,
//     one vmcnt(0)+barrier per K-tile, setprio around MFMA bursts.

#define NTOK 16384
#define DDIM 1024
#define NEXP 7
#define BM 256
#define BN 256
#define BK 64
#define NKT (DDIM / BK)

// ws ints / byte offsets
#define WI_OFFS   16          // [8]; offs[7] = nlin
#define WI_NTILES 32
#define WI_TABLE  64          // [72][2] {expert, crow0}
#define WI_CTOK   512         // [16384]: [0,nlin) slot->token; rest identity
#define WS_ABF_B  1048576                       // 32 MB bf16 A (compact)
#define WS_WBF_B  (WS_ABF_B + NTOK * DDIM * 2)  // 14 MB bf16 W

typedef __attribute__((ext_vector_type(8))) short short8;
typedef __attribute__((ext_vector_type(4))) float f32x4;

__device__ __forceinline__ unsigned short f2bf(float f) {
    unsigned u = __float_as_uint(f);
    u += 0x7fff + ((u >> 16) & 1);
    return (unsigned short)(u >> 16);
}

__device__ __forceinline__ void gload16(const void* g, void* l) {
    __builtin_amdgcn_global_load_lds(
        (const __attribute__((address_space(1))) void*)g,
        (__attribute__((address_space(3))) void*)l, 16, 0, 0);
}

// block 0: route via ballot (2-pass, no atomics). blocks 1..1792: W->bf16.
__global__ __launch_bounds__(256) void routeconv_k(
    const int* __restrict__ type, int* __restrict__ wsi,
    const float* __restrict__ W, unsigned short* __restrict__ Wbf) {
    const int bid = blockIdx.x, tid = threadIdx.x;
    if (bid == 0) {
        __shared__ int h[4][8];      // per-wave counts
        __shared__ int base2[4][8];  // per-wave scatter bases
        const int wave = tid >> 6, lane = tid & 63;
        const unsigned long long lt = (1ULL << lane) - 1;

        // pass 1: ballot count
        int cnt[8];
#pragma unroll
        for (int e = 0; e < 8; ++e) cnt[e] = 0;
        for (int i = 0; i < 64; ++i) {
            int k = type[i * 256 + tid];
#pragma unroll
            for (int e = 0; e < 8; ++e)
                cnt[e] += __popcll(__ballot(k == e));
        }
        if (lane == 0) {
#pragma unroll
            for (int e = 0; e < 8; ++e) h[wave][e] = cnt[e];
        }
        __syncthreads();

        if (tid == 0) {
            int acc = 0, t = 0;
            for (int e = 0; e < NEXP; ++e) {
                wsi[WI_OFFS + e] = acc;
                int run = acc;
                for (int w = 0; w < 4; ++w) { base2[w][e + 1] = run; run += h[w][e + 1]; }
                int nt = (run - acc + BM - 1) >> 8;
                for (int i = 0; i < nt; ++i) {
                    wsi[WI_TABLE + 2 * t] = e;
                    wsi[WI_TABLE + 2 * t + 1] = acc + i * BM;
                    ++t;
                }
                acc = run;
            }
            wsi[WI_OFFS + NEXP] = acc;
            wsi[WI_NTILES] = t;
            int run = acc;                       // identity list after linear
            for (int w = 0; w < 4; ++w) { base2[w][0] = run; run += h[w][0]; }
        }
        __syncthreads();

        // pass 2: ballot scatter (running bases in wave-uniform registers)
        int rb[8];
#pragma unroll
        for (int e = 0; e < 8; ++e) rb[e] = base2[wave][e];
        for (int i = 0; i < 64; ++i) {
            int t2 = i * 256 + tid;
            int k = type[t2];
            int pos = 0;
#pragma unroll
            for (int e = 0; e < 8; ++e) {
                unsigned long long m = __ballot(k == e);
                int p = rb[e] + __popcll(m & lt);
                pos = (k == e) ? p : pos;
                rb[e] += __popcll(m);
            }
            wsi[WI_CTOK + pos] = t2;
        }
    } else {
        size_t i = ((size_t)(bid - 1) * 256 + tid) * 16;
        const float4* src = (const float4*)(W + i);
        float4 v0 = src[0], v1 = src[1], v2 = src[2], v3 = src[3];
        short8 h0, h1;
        h0[0]=f2bf(v0.x); h0[1]=f2bf(v0.y); h0[2]=f2bf(v0.z); h0[3]=f2bf(v0.w);
        h0[4]=f2bf(v1.x); h0[5]=f2bf(v1.y); h0[6]=f2bf(v1.z); h0[7]=f2bf(v1.w);
        h1[0]=f2bf(v2.x); h1[1]=f2bf(v2.y); h1[2]=f2bf(v2.z); h1[3]=f2bf(v2.w);
        h1[4]=f2bf(v3.x); h1[5]=f2bf(v3.y); h1[6]=f2bf(v3.z); h1[7]=f2bf(v3.w);
        *(short8*)(Wbf + i) = h0;
        *(short8*)(Wbf + i + 8) = h1;
    }
}

// One wave per slot: linear -> gather+convert to Abf[s]; identity -> copy.
__global__ __launch_bounds__(256) void aconv_k(
    const float* __restrict__ A, const int* __restrict__ wsi,
    unsigned short* __restrict__ Abf, float* __restrict__ out) {
    const int wave = threadIdx.x >> 6, lane = threadIdx.x & 63;
    const int s = blockIdx.x * 4 + wave;
    const int nlin = wsi[WI_OFFS + NEXP];
    const int tok = wsi[WI_CTOK + s];
    const float4* src = (const float4*)(A + (size_t)tok * DDIM);
    if (s >= nlin) {
        float4* d = (float4*)(out + (size_t)tok * DDIM);
#pragma unroll
        for (int j = 0; j < 4; ++j) d[lane + j * 64] = src[lane + j * 64];
    } else {
        float4 v0 = src[lane * 4 + 0], v1 = src[lane * 4 + 1];
        float4 v2 = src[lane * 4 + 2], v3 = src[lane * 4 + 3];
        short8 h0, h1;
        h0[0]=f2bf(v0.x); h0[1]=f2bf(v0.y); h0[2]=f2bf(v0.z); h0[3]=f2bf(v0.w);
        h0[4]=f2bf(v1.x); h0[5]=f2bf(v1.y); h0[6]=f2bf(v1.z); h0[7]=f2bf(v1.w);
        h1[0]=f2bf(v2.x); h1[1]=f2bf(v2.y); h1[2]=f2bf(v2.z); h1[3]=f2bf(v2.w);
        h1[4]=f2bf(v3.x); h1[5]=f2bf(v3.y); h1[6]=f2bf(v3.z); h1[7]=f2bf(v3.w);
        unsigned short* d = Abf + (size_t)s * DDIM + lane * 16;
        *(short8*)d = h0;
        *(short8*)(d + 8) = h1;
    }
}

// One K-tile, R9's proven order: reads1 -> stage-issue next tile -> MFMA1
// -> reads2 -> MFMA2 -> vmcnt(0) -> barrier.
#define TILE(Abase, Bbase, sNA, sNB, KT)                           \
    do {                                                           \
        short8 a1[8], b1[4];                                       \
        _Pragma("unroll")                                          \
        for (int m = 0; m < 8; ++m)                                \
            a1[m] = *(const short8*)(Abase + sl0 + m * 2048);      \
        _Pragma("unroll")                                          \
        for (int n = 0; n < 4; ++n)                                \
            b1[n] = *(const short8*)(Bbase + sl0 + n * 2048);      \
        if ((KT) + 1 < NKT) {                                      \
            const int ke_ = ((KT) + 1) * BK;                       \
            _Pragma("unroll")                                      \
            for (int q = 0; q < 4; ++q)                            \
                gload16(aSrc[q] + ke_, sNA + q * 8192);            \
            _Pragma("unroll")                                      \
            for (int q = 0; q < 4; ++q)                            \
                gload16(bSrc[q] + ke_, sNB + q * 8192);            \
        }                                                          \
        __builtin_amdgcn_s_setprio(1);                             \
        _Pragma("unroll")                                          \
        for (int m = 0; m < 8; ++m)                                \
            _Pragma("unroll")                                      \
            for (int n = 0; n < 4; ++n)                            \
                acc[m][n] = __builtin_amdgcn_mfma_f32_16x16x32_bf16(\
                    a1[m], b1[n], acc[m][n], 0, 0, 0);             \
        __builtin_amdgcn_s_setprio(0);                             \
        short8 a2[8], b2[4];                                       \
        _Pragma("unroll")                                          \
        for (int m = 0; m < 8; ++m)                                \
            a2[m] = *(const short8*)(Abase + sl1 + m * 2048);      \
        _Pragma("unroll")                                          \
        for (int n = 0; n < 4; ++n)                                \
            b2[n] = *(const short8*)(Bbase + sl1 + n * 2048);      \
        __builtin_amdgcn_s_setprio(1);                             \
        _Pragma("unroll")                                          \
        for (int m = 0; m < 8; ++m)                                \
            _Pragma("unroll")                                      \
            for (int n = 0; n < 4; ++n)                            \
                acc[m][n] = __builtin_amdgcn_mfma_f32_16x16x32_bf16(\
                    a2[m], b2[n], acc[m][n], 0, 0, 0);             \
        __builtin_amdgcn_s_setprio(0);                             \
        asm volatile("s_waitcnt vmcnt(0)" ::: "memory");           \
        __builtin_amdgcn_s_barrier();                              \
    } while (0)

__global__ __launch_bounds__(512, 2) void gemm_k(
    const unsigned short* __restrict__ Abf,
    const unsigned short* __restrict__ Wbf,
    const float* __restrict__ bias, float* __restrict__ out,
    const int* __restrict__ wsi) {
    const int bid = blockIdx.x;              // 0..255, 1 per CU
    const int c = bid & 7;                   // XCD
    const int g = bid >> 3;
    const int ntiles = wsi[WI_NTILES];
    const int* offs = wsi + WI_OFFS;
    const int* tab  = wsi + WI_TABLE;
    const int* ctok = wsi + WI_CTOK;

    // 4 distinct LDS arrays (compile-time dbuf; no alias hazards).
    __shared__ unsigned short As0[BM * BK];   // 32 KB each
    __shared__ unsigned short As1[BM * BK];
    __shared__ unsigned short Bs0[BM * BK];
    __shared__ unsigned short Bs1[BM * BK];

    const int tid = threadIdx.x, lane = tid & 63, wave = tid >> 6;
    const int wr = wave >> 2, wc = wave & 3;     // wave-tile 128x64
    const int lane15 = lane & 15;
    const int srow = lane >> 3;                          // 0..7
    const int schunk = ((lane & 7) ^ srow) * 8;          // inverse-swizzled src

    const int sl0 = (((lane >> 4)) ^ (lane & 7)) * 16;
    const int sl1 = ((4 | (lane >> 4)) ^ (lane & 7)) * 16;
    const char* aR0 = (const char*)As0 + wr * 16384 + lane15 * 128;
    const char* aR1 = (const char*)As1 + wr * 16384 + lane15 * 128;
    const char* bR0 = (const char*)Bs0 + wc * 8192 + lane15 * 128;
    const char* bR1 = (const char*)Bs1 + wc * 8192 + lane15 * 128;
    char* sA0 = (char*)As0 + wave * 1024;
    char* sA1 = (char*)As1 + wave * 1024;
    char* sB0 = (char*)Bs0 + wave * 1024;
    char* sB1 = (char*)Bs1 + wave * 1024;

    for (int rep = 0; rep < 2; ++rep) {
        const int q4 = g + 32 * rep;
        const int ty = (q4 >> 2) * 8 + c;
        const int tx = q4 & 3;
        if (ty >= ntiles) break;

        const int e     = tab[2 * ty];
        const int crow0 = tab[2 * ty + 1];
        const int nend  = offs[e + 1];
        const int col0  = tx * BN;
        const unsigned short* Wb = Wbf + (size_t)e * DDIM * DDIM;

        const unsigned short* aSrc[4];
        const unsigned short* bSrc[4];
#pragma unroll
        for (int q = 0; q < 4; ++q) {
            int r = min(crow0 + q * 64 + wave * 8 + srow, NTOK - 1);
            aSrc[q] = Abf + (size_t)r * DDIM + schunk;
            bSrc[q] = Wb + (size_t)(col0 + q * 64 + wave * 8 + srow) * DDIM + schunk;
        }

        f32x4 acc[8][4];
#pragma unroll
        for (int m = 0; m < 8; ++m)
#pragma unroll
            for (int n = 0; n < 4; ++n) acc[m][n] = (f32x4){0.f, 0.f, 0.f, 0.f};

        // prologue: stage K-tile 0 into buf 0, gate
#pragma unroll
        for (int q = 0; q < 4; ++q) gload16(aSrc[q], sA0 + q * 8192);
#pragma unroll
        for (int q = 0; q < 4; ++q) gload16(bSrc[q], sB0 + q * 8192);
        asm volatile("s_waitcnt vmcnt(0)" ::: "memory");
        __builtin_amdgcn_s_barrier();

        for (int kt2 = 0; kt2 < NKT / 2; ++kt2) {
            TILE(aR0, bR0, sA1, sB1, 2 * kt2);
            TILE(aR1, bR1, sA0, sB0, 2 * kt2 + 1);
        }

        // epilogue: bias + gathered store (C/D: col=lane&15, row=(lane>>4)*4+r)
        const int crow4 = (lane >> 4) * 4;
        float bv[4];
#pragma unroll
        for (int n = 0; n < 4; ++n)
            bv[n] = bias[e * DDIM + col0 + wc * 64 + n * 16 + lane15];

#pragma unroll
        for (int m = 0; m < 8; ++m) {
#pragma unroll
            for (int r = 0; r < 4; ++r) {
                int gr = crow0 + wr * 128 + m * 16 + crow4 + r;
                if (gr >= nend) continue;
                int tok = ctok[gr];
                float* orow = out + (size_t)tok * DDIM + col0 + wc * 64 + lane15;
#pragma unroll
                for (int n = 0; n < 4; ++n)
                    orow[n * 16] = acc[m][n][r] + bv[n];
            }
        }
        __builtin_amdgcn_s_barrier();   // LDS quiesced before next rep's stage
    }
}

extern "C" void kernel_launch(void* const* d_in, const int* in_sizes, int n_in,
                              void* d_out, int out_size, void* d_ws, size_t ws_size,
                              hipStream_t stream) {
    const float* actions = (const float*)d_in[0];
    const int*   atype   = (const int*)d_in[1];
    const float* W       = (const float*)d_in[2];
    const float* bias    = (const float*)d_in[3];
    float* out = (float*)d_out;

    int* wsi = (int*)d_ws;
    unsigned short* Abf = (unsigned short*)((char*)d_ws + WS_ABF_B);
    unsigned short* Wbf = (unsigned short*)((char*)d_ws + WS_WBF_B);

    routeconv_k<<<1 + 1792, 256, 0, stream>>>(atype, wsi, W, Wbf);
    aconv_k<<<NTOK / 4, 256, 0, stream>>>(actions, wsi, Abf, out);
    gemm_k<<<256, 512, 0, stream>>>(Abf, Wbf, bias, out, wsi);
}

// Round 16
// 82.416 us; speedup vs baseline: 1.2429x; 1.2429x over previous
//
#include <hip/hip_runtime.h>

// B=32, L=512, D=1024; 7 linear experts + identity, routed per token.
// 3 launches:
//  K1 routeconv_k (1024-thr blocks): block 0 = route via ballot with
//     BATCHED int4 token loads (4-deep ILP; R15's 51us was a 64-deep
//     serial load chain, not atomics); blocks 1..448 = W f32->bf16.
//  K2 aconv_k: slot s -> gather+convert A row to Abf[s] or identity copy.
//  K3 gemm_k: R9's proven schedule: 256 blocks (1/CU), 256x256 tile,
//     8 waves (2Mx4N), BK=64, XOR-swizzled LDS, distinct-array dbuf,
//     one vmcnt(0)+barrier per K-tile, setprio around MFMA bursts.

#define NTOK 16384
#define DDIM 1024
#define NEXP 7
#define BM 256
#define BN 256
#define BK 64
#define NKT (DDIM / BK)

// ws ints / byte offsets
#define WI_OFFS   16          // [8]; offs[7] = nlin
#define WI_NTILES 32
#define WI_TABLE  64          // [72][2] {expert, crow0}
#define WI_CTOK   512         // [16384]: [0,nlin) slot->token; rest identity
#define WS_ABF_B  1048576                       // 32 MB bf16 A (compact)
#define WS_WBF_B  (WS_ABF_B + NTOK * DDIM * 2)  // 14 MB bf16 W

typedef __attribute__((ext_vector_type(8))) short short8;
typedef __attribute__((ext_vector_type(4))) float f32x4;

__device__ __forceinline__ unsigned short f2bf(float f) {
    unsigned u = __float_as_uint(f);
    u += 0x7fff + ((u >> 16) & 1);
    return (unsigned short)(u >> 16);
}

__device__ __forceinline__ void gload16(const void* g, void* l) {
    __builtin_amdgcn_global_load_lds(
        (const __attribute__((address_space(1))) void*)g,
        (__attribute__((address_space(3))) void*)l, 16, 0, 0);
}

// block 0: route (ballot, batched int4 loads, 16 tokens/thread).
// blocks 1..448: W f32->bf16 (16 floats/thread).
__global__ __launch_bounds__(1024) void routeconv_k(
    const int* __restrict__ type, int* __restrict__ wsi,
    const float* __restrict__ W, unsigned short* __restrict__ Wbf) {
    const int bid = blockIdx.x, tid = threadIdx.x;
    if (bid == 0) {
        __shared__ int h[16][8];      // per-wave counts
        __shared__ int base2[16][8];  // per-wave scatter bases
        const int wave = tid >> 6, lane = tid & 63;
        const unsigned long long lt = (1ULL << lane) - 1;

        // batched load: 16 contiguous tokens per thread, 4 x int4 (ILP=4)
        const int4* tsrc = (const int4*)(type + tid * 16);
        int4 v0 = tsrc[0], v1 = tsrc[1], v2 = tsrc[2], v3 = tsrc[3];
        int kv[16] = { v0.x, v0.y, v0.z, v0.w, v1.x, v1.y, v1.z, v1.w,
                       v2.x, v2.y, v2.z, v2.w, v3.x, v3.y, v3.z, v3.w };

        // pass 1: ballot count
        int cnt[8];
#pragma unroll
        for (int e = 0; e < 8; ++e) cnt[e] = 0;
#pragma unroll
        for (int i = 0; i < 16; ++i) {
#pragma unroll
            for (int e = 0; e < 8; ++e)
                cnt[e] += __popcll(__ballot(kv[i] == e));
        }
        if (lane == 0) {
#pragma unroll
            for (int e = 0; e < 8; ++e) h[wave][e] = cnt[e];
        }
        __syncthreads();

        if (tid == 0) {
            int acc = 0, t = 0;
            for (int e = 0; e < NEXP; ++e) {
                wsi[WI_OFFS + e] = acc;
                int run = acc;
                for (int w = 0; w < 16; ++w) { base2[w][e + 1] = run; run += h[w][e + 1]; }
                int nt = (run - acc + BM - 1) >> 8;
                for (int i = 0; i < nt; ++i) {
                    wsi[WI_TABLE + 2 * t] = e;
                    wsi[WI_TABLE + 2 * t + 1] = acc + i * BM;
                    ++t;
                }
                acc = run;
            }
            wsi[WI_OFFS + NEXP] = acc;
            wsi[WI_NTILES] = t;
            int run = acc;                       // identity list after linear
            for (int w = 0; w < 16; ++w) { base2[w][0] = run; run += h[w][0]; }
        }
        __syncthreads();

        // pass 2: ballot scatter (values already in registers)
        int rb[8];
#pragma unroll
        for (int e = 0; e < 8; ++e) rb[e] = base2[wave][e];
#pragma unroll
        for (int i = 0; i < 16; ++i) {
            int k = kv[i];
            int pos = 0;
#pragma unroll
            for (int e = 0; e < 8; ++e) {
                unsigned long long m = __ballot(k == e);
                int p = rb[e] + __popcll(m & lt);
                pos = (k == e) ? p : pos;
                rb[e] += __popcll(m);
            }
            wsi[WI_CTOK + pos] = tid * 16 + i;
        }
    } else {
        size_t i = ((size_t)(bid - 1) * 1024 + tid) * 16;
        const float4* src = (const float4*)(W + i);
        float4 v0 = src[0], v1 = src[1], v2 = src[2], v3 = src[3];
        short8 h0, h1;
        h0[0]=f2bf(v0.x); h0[1]=f2bf(v0.y); h0[2]=f2bf(v0.z); h0[3]=f2bf(v0.w);
        h0[4]=f2bf(v1.x); h0[5]=f2bf(v1.y); h0[6]=f2bf(v1.z); h0[7]=f2bf(v1.w);
        h1[0]=f2bf(v2.x); h1[1]=f2bf(v2.y); h1[2]=f2bf(v2.z); h1[3]=f2bf(v2.w);
        h1[4]=f2bf(v3.x); h1[5]=f2bf(v3.y); h1[6]=f2bf(v3.z); h1[7]=f2bf(v3.w);
        *(short8*)(Wbf + i) = h0;
        *(short8*)(Wbf + i + 8) = h1;
    }
}

// One wave per slot: linear -> gather+convert to Abf[s]; identity -> copy.
__global__ __launch_bounds__(256) void aconv_k(
    const float* __restrict__ A, const int* __restrict__ wsi,
    unsigned short* __restrict__ Abf, float* __restrict__ out) {
    const int wave = threadIdx.x >> 6, lane = threadIdx.x & 63;
    const int s = blockIdx.x * 4 + wave;
    const int nlin = wsi[WI_OFFS + NEXP];
    const int tok = wsi[WI_CTOK + s];
    const float4* src = (const float4*)(A + (size_t)tok * DDIM);
    if (s >= nlin) {
        float4* d = (float4*)(out + (size_t)tok * DDIM);
#pragma unroll
        for (int j = 0; j < 4; ++j) d[lane + j * 64] = src[lane + j * 64];
    } else {
        float4 v0 = src[lane * 4 + 0], v1 = src[lane * 4 + 1];
        float4 v2 = src[lane * 4 + 2], v3 = src[lane * 4 + 3];
        short8 h0, h1;
        h0[0]=f2bf(v0.x); h0[1]=f2bf(v0.y); h0[2]=f2bf(v0.z); h0[3]=f2bf(v0.w);
        h0[4]=f2bf(v1.x); h0[5]=f2bf(v1.y); h0[6]=f2bf(v1.z); h0[7]=f2bf(v1.w);
        h1[0]=f2bf(v2.x); h1[1]=f2bf(v2.y); h1[2]=f2bf(v2.z); h1[3]=f2bf(v2.w);
        h1[4]=f2bf(v3.x); h1[5]=f2bf(v3.y); h1[6]=f2bf(v3.z); h1[7]=f2bf(v3.w);
        unsigned short* d = Abf + (size_t)s * DDIM + lane * 16;
        *(short8*)d = h0;
        *(short8*)(d + 8) = h1;
    }
}

// One K-tile, R9's proven order: reads1 -> stage-issue next tile -> MFMA1
// -> reads2 -> MFMA2 -> vmcnt(0) -> barrier.
#define TILE(Abase, Bbase, sNA, sNB, KT)                           \
    do {                                                           \
        short8 a1[8], b1[4];                                       \
        _Pragma("unroll")                                          \
        for (int m = 0; m < 8; ++m)                                \
            a1[m] = *(const short8*)(Abase + sl0 + m * 2048);      \
        _Pragma("unroll")                                          \
        for (int n = 0; n < 4; ++n)                                \
            b1[n] = *(const short8*)(Bbase + sl0 + n * 2048);      \
        if ((KT) + 1 < NKT) {                                      \
            const int ke_ = ((KT) + 1) * BK;                       \
            _Pragma("unroll")                                      \
            for (int q = 0; q < 4; ++q)                            \
                gload16(aSrc[q] + ke_, sNA + q * 8192);            \
            _Pragma("unroll")                                      \
            for (int q = 0; q < 4; ++q)                            \
                gload16(bSrc[q] + ke_, sNB + q * 8192);            \
        }                                                          \
        __builtin_amdgcn_s_setprio(1);                             \
        _Pragma("unroll")                                          \
        for (int m = 0; m < 8; ++m)                                \
            _Pragma("unroll")                                      \
            for (int n = 0; n < 4; ++n)                            \
                acc[m][n] = __builtin_amdgcn_mfma_f32_16x16x32_bf16(\
                    a1[m], b1[n], acc[m][n], 0, 0, 0);             \
        __builtin_amdgcn_s_setprio(0);                             \
        short8 a2[8], b2[4];                                       \
        _Pragma("unroll")                                          \
        for (int m = 0; m < 8; ++m)                                \
            a2[m] = *(const short8*)(Abase + sl1 + m * 2048);      \
        _Pragma("unroll")                                          \
        for (int n = 0; n < 4; ++n)                                \
            b2[n] = *(const short8*)(Bbase + sl1 + n * 2048);      \
        __builtin_amdgcn_s_setprio(1);                             \
        _Pragma("unroll")                                          \
        for (int m = 0; m < 8; ++m)                                \
            _Pragma("unroll")                                      \
            for (int n = 0; n < 4; ++n)                            \
                acc[m][n] = __builtin_amdgcn_mfma_f32_16x16x32_bf16(\
                    a2[m], b2[n], acc[m][n], 0, 0, 0);             \
        __builtin_amdgcn_s_setprio(0);                             \
        asm volatile("s_waitcnt vmcnt(0)" ::: "memory");           \
        __builtin_amdgcn_s_barrier();                              \
    } while (0)

__global__ __launch_bounds__(512, 2) void gemm_k(
    const unsigned short* __restrict__ Abf,
    const unsigned short* __restrict__ Wbf,
    const float* __restrict__ bias, float* __restrict__ out,
    const int* __restrict__ wsi) {
    const int bid = blockIdx.x;              // 0..255, 1 per CU
    const int c = bid & 7;                   // XCD
    const int g = bid >> 3;
    const int ntiles = wsi[WI_NTILES];
    const int* offs = wsi + WI_OFFS;
    const int* tab  = wsi + WI_TABLE;
    const int* ctok = wsi + WI_CTOK;

    // 4 distinct LDS arrays (compile-time dbuf; no alias hazards).
    __shared__ unsigned short As0[BM * BK];   // 32 KB each
    __shared__ unsigned short As1[BM * BK];
    __shared__ unsigned short Bs0[BM * BK];
    __shared__ unsigned short Bs1[BM * BK];

    const int tid = threadIdx.x, lane = tid & 63, wave = tid >> 6;
    const int wr = wave >> 2, wc = wave & 3;     // wave-tile 128x64
    const int lane15 = lane & 15;
    const int srow = lane >> 3;                          // 0..7
    const int schunk = ((lane & 7) ^ srow) * 8;          // inverse-swizzled src

    const int sl0 = (((lane >> 4)) ^ (lane & 7)) * 16;
    const int sl1 = ((4 | (lane >> 4)) ^ (lane & 7)) * 16;
    const char* aR0 = (const char*)As0 + wr * 16384 + lane15 * 128;
    const char* aR1 = (const char*)As1 + wr * 16384 + lane15 * 128;
    const char* bR0 = (const char*)Bs0 + wc * 8192 + lane15 * 128;
    const char* bR1 = (const char*)Bs1 + wc * 8192 + lane15 * 128;
    char* sA0 = (char*)As0 + wave * 1024;
    char* sA1 = (char*)As1 + wave * 1024;
    char* sB0 = (char*)Bs0 + wave * 1024;
    char* sB1 = (char*)Bs1 + wave * 1024;

    for (int rep = 0; rep < 2; ++rep) {
        const int q4 = g + 32 * rep;
        const int ty = (q4 >> 2) * 8 + c;
        const int tx = q4 & 3;
        if (ty >= ntiles) break;

        const int e     = tab[2 * ty];
        const int crow0 = tab[2 * ty + 1];
        const int nend  = offs[e + 1];
        const int col0  = tx * BN;
        const unsigned short* Wb = Wbf + (size_t)e * DDIM * DDIM;

        const unsigned short* aSrc[4];
        const unsigned short* bSrc[4];
#pragma unroll
        for (int q = 0; q < 4; ++q) {
            int r = min(crow0 + q * 64 + wave * 8 + srow, NTOK - 1);
            aSrc[q] = Abf + (size_t)r * DDIM + schunk;
            bSrc[q] = Wb + (size_t)(col0 + q * 64 + wave * 8 + srow) * DDIM + schunk;
        }

        f32x4 acc[8][4];
#pragma unroll
        for (int m = 0; m < 8; ++m)
#pragma unroll
            for (int n = 0; n < 4; ++n) acc[m][n] = (f32x4){0.f, 0.f, 0.f, 0.f};

        // prologue: stage K-tile 0 into buf 0, gate
#pragma unroll
        for (int q = 0; q < 4; ++q) gload16(aSrc[q], sA0 + q * 8192);
#pragma unroll
        for (int q = 0; q < 4; ++q) gload16(bSrc[q], sB0 + q * 8192);
        asm volatile("s_waitcnt vmcnt(0)" ::: "memory");
        __builtin_amdgcn_s_barrier();

        for (int kt2 = 0; kt2 < NKT / 2; ++kt2) {
            TILE(aR0, bR0, sA1, sB1, 2 * kt2);
            TILE(aR1, bR1, sA0, sB0, 2 * kt2 + 1);
        }

        // epilogue: bias + gathered store (C/D: col=lane&15, row=(lane>>4)*4+r)
        const int crow4 = (lane >> 4) * 4;
        float bv[4];
#pragma unroll
        for (int n = 0; n < 4; ++n)
            bv[n] = bias[e * DDIM + col0 + wc * 64 + n * 16 + lane15];

#pragma unroll
        for (int m = 0; m < 8; ++m) {
#pragma unroll
            for (int r = 0; r < 4; ++r) {
                int gr = crow0 + wr * 128 + m * 16 + crow4 + r;
                if (gr >= nend) continue;
                int tok = ctok[gr];
                float* orow = out + (size_t)tok * DDIM + col0 + wc * 64 + lane15;
#pragma unroll
                for (int n = 0; n < 4; ++n)
                    orow[n * 16] = acc[m][n][r] + bv[n];
            }
        }
        __builtin_amdgcn_s_barrier();   // LDS quiesced before next rep's stage
    }
}

extern "C" void kernel_launch(void* const* d_in, const int* in_sizes, int n_in,
                              void* d_out, int out_size, void* d_ws, size_t ws_size,
                              hipStream_t stream) {
    const float* actions = (const float*)d_in[0];
    const int*   atype   = (const int*)d_in[1];
    const float* W       = (const float*)d_in[2];
    const float* bias    = (const float*)d_in[3];
    float* out = (float*)d_out;

    int* wsi = (int*)d_ws;
    unsigned short* Abf = (unsigned short*)((char*)d_ws + WS_ABF_B);
    unsigned short* Wbf = (unsigned short*)((char*)d_ws + WS_WBF_B);

    routeconv_k<<<1 + 448, 1024, 0, stream>>>(atype, wsi, W, Wbf);
    aconv_k<<<NTOK / 4, 256, 0, stream>>>(actions, wsi, Abf, out);
    gemm_k<<<256, 512, 0, stream>>>(Abf, Wbf, bias, out, wsi);
}

// Round 17
// 69.358 us; speedup vs baseline: 1.4769x; 1.1883x over previous
//
#include <hip/hip_runtime.h>

// B=32, L=512, D=1024; 7 linear experts + identity, routed per token.
// 2 launches:
//  K1 prep_k (1024-thr, 1473 blocks, fully parallel):
//     block 0          = route via ballot (batched int4 loads), linear
//                        slots only -> ctok[0..nlin)
//     blocks 1..448    = W f32->bf16
//     blocks 449..1472 = A rows: type==0 -> f32 copy to out (identity);
//                        else f32->bf16 to Abf[token] (TOKEN order -- no
//                        compaction; gemm gathers via ctok at staging,
//                        since global_load_lds's global src is per-lane).
//  K2 gemm_k: R9's proven schedule: 256 blocks (1/CU), 256x256 tile,
//     8 waves (2Mx4N), BK=64, XOR-swizzled LDS, distinct-array dbuf,
//     one vmcnt(0)+barrier per K-tile, setprio; A rows gathered by ctok.

#define NTOK 16384
#define DDIM 1024
#define NEXP 7
#define BM 256
#define BN 256
#define BK 64
#define NKT (DDIM / BK)

// ws ints / byte offsets
#define WI_OFFS   16          // [8]; offs[7] = nlin
#define WI_NTILES 32
#define WI_TABLE  64          // [72][2] {expert, crow0}
#define WI_CTOK   512         // [0,nlin): slot -> token
#define WS_ABF_B  1048576                       // 32 MB bf16 A (token order)
#define WS_WBF_B  (WS_ABF_B + NTOK * DDIM * 2)  // 14 MB bf16 W

typedef __attribute__((ext_vector_type(8))) short short8;
typedef __attribute__((ext_vector_type(4))) float f32x4;

__device__ __forceinline__ unsigned short f2bf(float f) {
    unsigned u = __float_as_uint(f);
    u += 0x7fff + ((u >> 16) & 1);
    return (unsigned short)(u >> 16);
}

__device__ __forceinline__ void gload16(const void* g, void* l) {
    __builtin_amdgcn_global_load_lds(
        (const __attribute__((address_space(1))) void*)g,
        (__attribute__((address_space(3))) void*)l, 16, 0, 0);
}

__global__ __launch_bounds__(1024) void prep_k(
    const int* __restrict__ type, int* __restrict__ wsi,
    const float* __restrict__ W, unsigned short* __restrict__ Wbf,
    const float* __restrict__ A, unsigned short* __restrict__ Abf,
    float* __restrict__ out) {
    const int bid = blockIdx.x, tid = threadIdx.x;
    if (bid == 0) {
        // ---- route: ballot count + scatter, batched int4 token loads ----
        __shared__ int h[16][8];
        __shared__ int base2[16][8];
        const int wave = tid >> 6, lane = tid & 63;
        const unsigned long long lt = (1ULL << lane) - 1;

        const int4* tsrc = (const int4*)(type + tid * 16);
        int4 v0 = tsrc[0], v1 = tsrc[1], v2 = tsrc[2], v3 = tsrc[3];
        int kv[16] = { v0.x, v0.y, v0.z, v0.w, v1.x, v1.y, v1.z, v1.w,
                       v2.x, v2.y, v2.z, v2.w, v3.x, v3.y, v3.z, v3.w };

        int cnt[8];
#pragma unroll
        for (int e = 0; e < 8; ++e) cnt[e] = 0;
#pragma unroll
        for (int i = 0; i < 16; ++i) {
#pragma unroll
            for (int e = 1; e < 8; ++e)
                cnt[e] += __popcll(__ballot(kv[i] == e));
        }
        if (lane == 0) {
#pragma unroll
            for (int e = 0; e < 8; ++e) h[wave][e] = cnt[e];
        }
        __syncthreads();

        if (tid == 0) {
            int acc = 0, t = 0;
            for (int e = 0; e < NEXP; ++e) {
                wsi[WI_OFFS + e] = acc;
                int run = acc;
                for (int w = 0; w < 16; ++w) { base2[w][e + 1] = run; run += h[w][e + 1]; }
                int nt = (run - acc + BM - 1) >> 8;
                for (int i = 0; i < nt; ++i) {
                    wsi[WI_TABLE + 2 * t] = e;
                    wsi[WI_TABLE + 2 * t + 1] = acc + i * BM;
                    ++t;
                }
                acc = run;
            }
            wsi[WI_OFFS + NEXP] = acc;
            wsi[WI_NTILES] = t;
        }
        __syncthreads();

        int rb[8];
#pragma unroll
        for (int e = 1; e < 8; ++e) rb[e] = base2[wave][e];
#pragma unroll
        for (int i = 0; i < 16; ++i) {
            int k = kv[i];
            int pos = -1;
#pragma unroll
            for (int e = 1; e < 8; ++e) {
                unsigned long long m = __ballot(k == e);
                int p = rb[e] + __popcll(m & lt);
                pos = (k == e) ? p : pos;
                rb[e] += __popcll(m);
            }
            if (k > 0) wsi[WI_CTOK + pos] = tid * 16 + i;
        }
    } else if (bid <= 448) {
        // ---- W f32 -> bf16 ----
        size_t i = ((size_t)(bid - 1) * 1024 + tid) * 16;
        const float4* src = (const float4*)(W + i);
        float4 v0 = src[0], v1 = src[1], v2 = src[2], v3 = src[3];
        short8 h0, h1;
        h0[0]=f2bf(v0.x); h0[1]=f2bf(v0.y); h0[2]=f2bf(v0.z); h0[3]=f2bf(v0.w);
        h0[4]=f2bf(v1.x); h0[5]=f2bf(v1.y); h0[6]=f2bf(v1.z); h0[7]=f2bf(v1.w);
        h1[0]=f2bf(v2.x); h1[1]=f2bf(v2.y); h1[2]=f2bf(v2.z); h1[3]=f2bf(v2.w);
        h1[4]=f2bf(v3.x); h1[5]=f2bf(v3.y); h1[6]=f2bf(v3.z); h1[7]=f2bf(v3.w);
        *(short8*)(Wbf + i) = h0;
        *(short8*)(Wbf + i + 8) = h1;
    } else {
        // ---- A rows (token order): identity copy or convert ----
        const int wave = tid >> 6, lane = tid & 63;
        const int t = (bid - 449) * 16 + wave;
        const float4* src = (const float4*)(A + (size_t)t * DDIM);
        if (type[t] == 0) {
            float4* d = (float4*)(out + (size_t)t * DDIM);
#pragma unroll
            for (int j = 0; j < 4; ++j) d[lane + j * 64] = src[lane + j * 64];
        } else {
            float4 v0 = src[lane * 4 + 0], v1 = src[lane * 4 + 1];
            float4 v2 = src[lane * 4 + 2], v3 = src[lane * 4 + 3];
            short8 h0, h1;
            h0[0]=f2bf(v0.x); h0[1]=f2bf(v0.y); h0[2]=f2bf(v0.z); h0[3]=f2bf(v0.w);
            h0[4]=f2bf(v1.x); h0[5]=f2bf(v1.y); h0[6]=f2bf(v1.z); h0[7]=f2bf(v1.w);
            h1[0]=f2bf(v2.x); h1[1]=f2bf(v2.y); h1[2]=f2bf(v2.z); h1[3]=f2bf(v2.w);
            h1[4]=f2bf(v3.x); h1[5]=f2bf(v3.y); h1[6]=f2bf(v3.z); h1[7]=f2bf(v3.w);
            unsigned short* d = Abf + (size_t)t * DDIM + lane * 16;
            *(short8*)d = h0;
            *(short8*)(d + 8) = h1;
        }
    }
}

// One K-tile, R9's proven order: reads1 -> stage-issue next tile -> MFMA1
// -> reads2 -> MFMA2 -> vmcnt(0) -> barrier.
#define TILE(Abase, Bbase, sNA, sNB, KT)                           \
    do {                                                           \
        short8 a1[8], b1[4];                                       \
        _Pragma("unroll")                                          \
        for (int m = 0; m < 8; ++m)                                \
            a1[m] = *(const short8*)(Abase + sl0 + m * 2048);      \
        _Pragma("unroll")                                          \
        for (int n = 0; n < 4; ++n)                                \
            b1[n] = *(const short8*)(Bbase + sl0 + n * 2048);      \
        if ((KT) + 1 < NKT) {                                      \
            const int ke_ = ((KT) + 1) * BK;                       \
            _Pragma("unroll")                                      \
            for (int q = 0; q < 4; ++q)                            \
                gload16(aSrc[q] + ke_, sNA + q * 8192);            \
            _Pragma("unroll")                                      \
            for (int q = 0; q < 4; ++q)                            \
                gload16(bSrc[q] + ke_, sNB + q * 8192);            \
        }                                                          \
        __builtin_amdgcn_s_setprio(1);                             \
        _Pragma("unroll")                                          \
        for (int m = 0; m < 8; ++m)                                \
            _Pragma("unroll")                                      \
            for (int n = 0; n < 4; ++n)                            \
                acc[m][n] = __builtin_amdgcn_mfma_f32_16x16x32_bf16(\
                    a1[m], b1[n], acc[m][n], 0, 0, 0);             \
        __builtin_amdgcn_s_setprio(0);                             \
        short8 a2[8], b2[4];                                       \
        _Pragma("unroll")                                          \
        for (int m = 0; m < 8; ++m)                                \
            a2[m] = *(const short8*)(Abase + sl1 + m * 2048);      \
        _Pragma("unroll")                                          \
        for (int n = 0; n < 4; ++n)                                \
            b2[n] = *(const short8*)(Bbase + sl1 + n * 2048);      \
        __builtin_amdgcn_s_setprio(1);                             \
        _Pragma("unroll")                                          \
        for (int m = 0; m < 8; ++m)                                \
            _Pragma("unroll")                                      \
            for (int n = 0; n < 4; ++n)                            \
                acc[m][n] = __builtin_amdgcn_mfma_f32_16x16x32_bf16(\
                    a2[m], b2[n], acc[m][n], 0, 0, 0);             \
        __builtin_amdgcn_s_setprio(0);                             \
        asm volatile("s_waitcnt vmcnt(0)" ::: "memory");           \
        __builtin_amdgcn_s_barrier();                              \
    } while (0)

__global__ __launch_bounds__(512, 2) void gemm_k(
    const unsigned short* __restrict__ Abf,
    const unsigned short* __restrict__ Wbf,
    const float* __restrict__ bias, float* __restrict__ out,
    const int* __restrict__ wsi) {
    const int bid = blockIdx.x;              // 0..255, 1 per CU
    const int c = bid & 7;                   // XCD
    const int g = bid >> 3;
    const int ntiles = wsi[WI_NTILES];
    const int* offs = wsi + WI_OFFS;
    const int* tab  = wsi + WI_TABLE;
    const int* ctok = wsi + WI_CTOK;
    const int nlin  = offs[NEXP];

    // 4 distinct LDS arrays (compile-time dbuf; no alias hazards).
    __shared__ unsigned short As0[BM * BK];   // 32 KB each
    __shared__ unsigned short As1[BM * BK];
    __shared__ unsigned short Bs0[BM * BK];
    __shared__ unsigned short Bs1[BM * BK];

    const int tid = threadIdx.x, lane = tid & 63, wave = tid >> 6;
    const int wr = wave >> 2, wc = wave & 3;     // wave-tile 128x64
    const int lane15 = lane & 15;
    const int srow = lane >> 3;                          // 0..7
    const int schunk = ((lane & 7) ^ srow) * 8;          // inverse-swizzled src

    const int sl0 = (((lane >> 4)) ^ (lane & 7)) * 16;
    const int sl1 = ((4 | (lane >> 4)) ^ (lane & 7)) * 16;
    const char* aR0 = (const char*)As0 + wr * 16384 + lane15 * 128;
    const char* aR1 = (const char*)As1 + wr * 16384 + lane15 * 128;
    const char* bR0 = (const char*)Bs0 + wc * 8192 + lane15 * 128;
    const char* bR1 = (const char*)Bs1 + wc * 8192 + lane15 * 128;
    char* sA0 = (char*)As0 + wave * 1024;
    char* sA1 = (char*)As1 + wave * 1024;
    char* sB0 = (char*)Bs0 + wave * 1024;
    char* sB1 = (char*)Bs1 + wave * 1024;

    for (int rep = 0; rep < 2; ++rep) {
        const int q4 = g + 32 * rep;
        const int ty = (q4 >> 2) * 8 + c;
        const int tx = q4 & 3;
        if (ty >= ntiles) break;

        const int e     = tab[2 * ty];
        const int crow0 = tab[2 * ty + 1];
        const int nend  = offs[e + 1];
        const int col0  = tx * BN;
        const unsigned short* Wb = Wbf + (size_t)e * DDIM * DDIM;

        const unsigned short* aSrc[4];
        const unsigned short* bSrc[4];
#pragma unroll
        for (int q = 0; q < 4; ++q) {
            int r = min(crow0 + q * 64 + wave * 8 + srow, nlin - 1);
            aSrc[q] = Abf + (size_t)ctok[r] * DDIM + schunk;   // token-gather
            bSrc[q] = Wb + (size_t)(col0 + q * 64 + wave * 8 + srow) * DDIM + schunk;
        }

        f32x4 acc[8][4];
#pragma unroll
        for (int m = 0; m < 8; ++m)
#pragma unroll
            for (int n = 0; n < 4; ++n) acc[m][n] = (f32x4){0.f, 0.f, 0.f, 0.f};

        // prologue: stage K-tile 0 into buf 0, gate
#pragma unroll
        for (int q = 0; q < 4; ++q) gload16(aSrc[q], sA0 + q * 8192);
#pragma unroll
        for (int q = 0; q < 4; ++q) gload16(bSrc[q], sB0 + q * 8192);
        asm volatile("s_waitcnt vmcnt(0)" ::: "memory");
        __builtin_amdgcn_s_barrier();

        for (int kt2 = 0; kt2 < NKT / 2; ++kt2) {
            TILE(aR0, bR0, sA1, sB1, 2 * kt2);
            TILE(aR1, bR1, sA0, sB0, 2 * kt2 + 1);
        }

        // epilogue: bias + gathered store (C/D: col=lane&15, row=(lane>>4)*4+r)
        const int crow4 = (lane >> 4) * 4;
        float bv[4];
#pragma unroll
        for (int n = 0; n < 4; ++n)
            bv[n] = bias[e * DDIM + col0 + wc * 64 + n * 16 + lane15];

#pragma unroll
        for (int m = 0; m < 8; ++m) {
#pragma unroll
            for (int r = 0; r < 4; ++r) {
                int gr = crow0 + wr * 128 + m * 16 + crow4 + r;
                if (gr >= nend) continue;
                int tok = ctok[gr];
                float* orow = out + (size_t)tok * DDIM + col0 + wc * 64 + lane15;
#pragma unroll
                for (int n = 0; n < 4; ++n)
                    orow[n * 16] = acc[m][n][r] + bv[n];
            }
        }
        __builtin_amdgcn_s_barrier();   // LDS quiesced before next rep's stage
    }
}

extern "C" void kernel_launch(void* const* d_in, const int* in_sizes, int n_in,
                              void* d_out, int out_size, void* d_ws, size_t ws_size,
                              hipStream_t stream) {
    const float* actions = (const float*)d_in[0];
    const int*   atype   = (const int*)d_in[1];
    const float* W       = (const float*)d_in[2];
    const float* bias    = (const float*)d_in[3];
    float* out = (float*)d_out;

    int* wsi = (int*)d_ws;
    unsigned short* Abf = (unsigned short*)((char*)d_ws + WS_ABF_B);
    unsigned short* Wbf = (unsigned short*)((char*)d_ws + WS_WBF_B);

    prep_k<<<1473, 1024, 0, stream>>>(atype, wsi, W, Wbf, actions, Abf, out);
    gemm_k<<<256, 512, 0, stream>>>(Abf, Wbf, bias, out, wsi);
}